// Round 2
// baseline (471.253 us; speedup 1.0000x reference)
//
#include <hip/hip_runtime.h>

typedef _Float16 f16;

__device__ __forceinline__ float sigm(float x) {
    return __builtin_amdgcn_rcpf(1.0f + __expf(-x));
}
__device__ __forceinline__ float tanh_fast(float x) {
    // tanh(x) = 1 - 2/(1+e^{2x}); stable at both tails (inf -> 1, 0 -> -1)
    return 1.0f - 2.0f * __builtin_amdgcn_rcpf(1.0f + __expf(2.0f * x));
}

// Producer: one thread per (b, tc) row of the chunk. Computes
// u = relu(W1 x + b1); xg = W_ih u + b_ih + b_hh; stores fp16 [b][tc][64].
// Weight accesses are uniform+unrolled -> SGPR (s_load) operands.
__global__ __launch_bounds__(256) void xg_producer(
    const float* __restrict__ x,
    const float* __restrict__ W1, const float* __restrict__ b1,
    const float* __restrict__ Wih, const float* __restrict__ bih,
    const float* __restrict__ bhh,
    unsigned* __restrict__ xg32, int t0, int tcShift)
{
    __shared__ unsigned lds[4][64][36];   // pad 36 keeps rows 16B-aligned
    const int tid  = threadIdx.x;
    const int lane = tid & 63, w = tid >> 6;
    const int idx  = blockIdx.x * 256 + tid;
    const int tc   = idx & ((1 << tcShift) - 1);
    const int b    = idx >> tcShift;

    const float4* xv = (const float4*)(x + ((size_t)b * 512 + (size_t)(t0 + tc)) * 12);
    float4 a0 = xv[0], a1 = xv[1], a2 = xv[2];
    float xr[12] = {a0.x,a0.y,a0.z,a0.w, a1.x,a1.y,a1.z,a1.w, a2.x,a2.y,a2.z,a2.w};

    float u[32];
#pragma unroll
    for (int f = 0; f < 32; ++f) {
        float acc = b1[f];
#pragma unroll
        for (int i = 0; i < 12; ++i) acc = fmaf(W1[f*12 + i], xr[i], acc);
        u[f] = fmaxf(acc, 0.0f);
    }

#pragma unroll
    for (int d = 0; d < 32; ++d) {
        float ae = bih[2*d]     + bhh[2*d];
        float ao = bih[2*d + 1] + bhh[2*d + 1];
#pragma unroll
        for (int f = 0; f < 32; ++f) {
            ae = fmaf(Wih[(2*d)*32 + f],     u[f], ae);
            ao = fmaf(Wih[(2*d + 1)*32 + f], u[f], ao);
        }
        auto p = __builtin_amdgcn_cvt_pkrtz(ae, ao);   // __fp16 ext_vector(2)
        lds[w][lane][d] = __builtin_bit_cast(unsigned, p);
    }
    __syncthreads();
    // Coalesced store of this wave's 64 contiguous rows (64 x 32 dwords).
    const size_t wbase = ((size_t)blockIdx.x * 256 + (size_t)(tid & 192)) * 32;
#pragma unroll
    for (int it = 0; it < 32; ++it) {
        int o = it * 64 + lane;
        xg32[wbase + o] = lds[w][o >> 5][o & 31];
    }
}

// Consumer: 16 lanes per batch element, 4 elements per wave, 1 wave per block.
// Lane (e,h) owns hidden unit h: W_hh rows {h,h+16,h+32,h+48} in registers.
__global__ __launch_bounds__(64) void lstm_chunk(
    const f16* __restrict__ xg,
    const float* __restrict__ Whh,
    const float* __restrict__ h_in, const float* __restrict__ c_in,
    float* __restrict__ h_st, float* __restrict__ c_st,
    const float* __restrict__ W2, const float* __restrict__ b2,
    float* __restrict__ dout,
    int Tc, int last)
{
    const int lane = threadIdx.x;
    const int h = lane & 15, e = lane >> 4;
    const int b = blockIdx.x * 4 + e;

    float hs = h_in[b*16 + h];
    float cs = c_in[b*16 + h];

    float wi[16], wf[16], wg[16], wo[16];
    {
        const float4* W = (const float4*)Whh;   // rows are 64B, aligned
#pragma unroll
        for (int k4 = 0; k4 < 4; ++k4) {
            float4 vi = W[(h)     *4 + k4];
            float4 vf = W[(h + 16)*4 + k4];
            float4 vg = W[(h + 32)*4 + k4];
            float4 vo = W[(h + 48)*4 + k4];
            wi[4*k4]=vi.x; wi[4*k4+1]=vi.y; wi[4*k4+2]=vi.z; wi[4*k4+3]=vi.w;
            wf[4*k4]=vf.x; wf[4*k4+1]=vf.y; wf[4*k4+2]=vf.z; wf[4*k4+3]=vf.w;
            wg[4*k4]=vg.x; wg[4*k4+1]=vg.y; wg[4*k4+2]=vg.z; wg[4*k4+3]=vg.w;
            wo[4*k4]=vo.x; wo[4*k4+1]=vo.y; wo[4*k4+2]=vo.z; wo[4*k4+3]=vo.w;
        }
    }

    const f16* xp = xg + (size_t)b * Tc * 64 + h;
    // 1-step-ahead prefetch; final over-read lands in the state region of ws.
    float n0 = (float)xp[0], n1 = (float)xp[16], n2 = (float)xp[32], n3 = (float)xp[48];

    for (int tc = 0; tc < Tc; ++tc) {
        float gi = n0, gf = n1, gg = n2, go = n3;
        xp += 64;
        n0 = (float)xp[0]; n1 = (float)xp[16]; n2 = (float)xp[32]; n3 = (float)xp[48];
#pragma unroll
        for (int k = 0; k < 16; ++k) {
            float hk = __shfl(hs, (lane & 48) | k);
            gi = fmaf(wi[k], hk, gi);
            gf = fmaf(wf[k], hk, gf);
            gg = fmaf(wg[k], hk, gg);
            go = fmaf(wo[k], hk, go);
        }
        float tg = tanh_fast(gg);
        float si = sigm(gi);
        cs = fmaf(sigm(gf), cs, si * tg);
        hs = sigm(go) * tanh_fast(cs);
    }

    h_st[b*16 + h] = hs;
    c_st[b*16 + h] = cs;

    if (last) {
        dout[4096 + b*16 + h]         = hs;   // hT [1,B,H]
        dout[4096 + 65536 + b*16 + h] = cs;   // cT [1,B,H]
        float p = hs * W2[h];
        p += __shfl_xor(p, 1);
        p += __shfl_xor(p, 2);
        p += __shfl_xor(p, 4);
        p += __shfl_xor(p, 8);
        if (h == 0) dout[b] = tanh_fast(p + b2[0]);   // out [B,1]
    }
}

extern "C" void kernel_launch(void* const* d_in, const int* in_sizes, int n_in,
                              void* d_out, int out_size, void* d_ws, size_t ws_size,
                              hipStream_t stream)
{
    const float* x   = (const float*)d_in[0];
    const float* h0  = (const float*)d_in[1];
    const float* c0  = (const float*)d_in[2];
    const float* W1  = (const float*)d_in[3];
    const float* b1  = (const float*)d_in[4];
    const float* Wih = (const float*)d_in[5];
    const float* Whh = (const float*)d_in[6];
    const float* bih = (const float*)d_in[7];
    const float* bhh = (const float*)d_in[8];
    const float* W2  = (const float*)d_in[9];
    const float* b2  = (const float*)d_in[10];
    float* out = (float*)d_out;

    // Chunk size: prefer Tc=128 (xg chunk = 64MB, L3-resident); shrink to fit ws.
    const size_t state_bytes = (size_t)2 * 65536 * 4 + 256;
    int tcShift = 7;
    while (tcShift > 0 &&
           ((size_t)4096 * ((size_t)64 << tcShift) * 2 + state_bytes) > ws_size)
        tcShift--;
    const int Tc = 1 << tcShift;
    const size_t xg_bytes = (size_t)4096 * Tc * 64 * 2;

    f16*   xg   = (f16*)d_ws;
    float* h_st = (float*)((char*)d_ws + xg_bytes);
    float* c_st = h_st + 65536;

    const int nchunk = 512 / Tc;
    for (int c = 0; c < nchunk; ++c) {
        const int t0 = c * Tc;
        const int pblocks = (4096 * Tc) / 256;
        xg_producer<<<dim3(pblocks), dim3(256), 0, stream>>>(
            x, W1, b1, Wih, bih, bhh, (unsigned*)xg, t0, tcShift);
        const float* hi = (c == 0) ? h0 : h_st;
        const float* ci = (c == 0) ? c0 : c_st;
        lstm_chunk<<<dim3(1024), dim3(64), 0, stream>>>(
            xg, Whh, hi, ci, h_st, c_st, W2, b2, out,
            Tc, (c == nchunk - 1) ? 1 : 0);
    }
}

// Round 3
// 223.513 us; speedup vs baseline: 2.1084x; 2.1084x over previous
//
#include <hip/hip_runtime.h>

typedef __fp16 f16;
typedef __attribute__((ext_vector_type(4))) __fp16 h16x4;
typedef __attribute__((ext_vector_type(4))) float f32x4;

__device__ __forceinline__ float sigm(float x) {
    return __builtin_amdgcn_rcpf(1.0f + __expf(-x));
}
__device__ __forceinline__ float tanh_fast(float x) {
    return 1.0f - 2.0f * __builtin_amdgcn_rcpf(1.0f + __expf(2.0f * x));
}
__device__ __forceinline__ h16x4 cvt4(float4 v) {
    h16x4 r; r[0] = (f16)v.x; r[1] = (f16)v.y; r[2] = (f16)v.z; r[3] = (f16)v.w;
    return r;
}

// MFMA producer. Per wave: one batch element b, Tc rows, 16 rows/tile.
// GEMM1 swapped (D' = W1 @ x^T) so D'-frag == A-frag of GEMM2 directly.
// Output layout: xg[b][t][h*4 + {i,f,g,o}] fp16 (uint2 per (t,h)).
__global__ __launch_bounds__(256) void xg_producer(
    const float* __restrict__ x,
    const float* __restrict__ W1, const float* __restrict__ b1,
    const float* __restrict__ Wih, const float* __restrict__ bih,
    const float* __restrict__ bhh,
    uint2* __restrict__ xg, int t0, int Tc)
{
    const int lane = threadIdx.x & 63, w = threadIdx.x >> 6;
    const int m = lane & 15, hi = lane >> 4;
    const int b = blockIdx.x * 4 + w;

    // GEMM1: A = W1 (n x k, k=12 padded to 16), acc-init = b1[n].
    h16x4 a1[2]; f32x4 c1[2];
#pragma unroll
    for (int nt = 0; nt < 2; ++nt) {
        float4 wv = make_float4(0.f, 0.f, 0.f, 0.f);
        if (hi < 3) wv = *(const float4*)(W1 + (nt * 16 + m) * 12 + 4 * hi);
        a1[nt] = cvt4(wv);
        float4 bv = *(const float4*)(b1 + nt * 16 + 4 * hi);
        c1[nt] = f32x4{bv.x, bv.y, bv.z, bv.w};
    }
    // GEMM2: B[k][n2] = Wih[n2][k]; n2 = 16*g + m; two K-steps of 16.
    h16x4 b2[4][2]; float cb[4];
#pragma unroll
    for (int g = 0; g < 4; ++g) {
        const int n = g * 16 + m;
#pragma unroll
        for (int s = 0; s < 2; ++s) {
            float4 wv = *(const float4*)(Wih + n * 32 + s * 16 + 4 * hi);
            b2[g][s] = cvt4(wv);
        }
        cb[g] = bih[n] + bhh[n];
    }

    const float* xb = x + ((size_t)b * 512 + t0) * 12;
    uint2* outp = xg + (size_t)b * Tc * 16;

    const int ntiles = Tc >> 4;
    for (int tile = 0; tile < ntiles; ++tile) {
        const int row0 = tile * 16;
        h16x4 bx = {0, 0, 0, 0};
        if (hi < 3) {
            float4 xv = *(const float4*)(xb + (row0 + m) * 12 + 4 * hi);
            bx = cvt4(xv);
        }
        f32x4 d0 = __builtin_amdgcn_mfma_f32_16x16x16f16(a1[0], bx, c1[0], 0, 0, 0);
        f32x4 d1 = __builtin_amdgcn_mfma_f32_16x16x16f16(a1[1], bx, c1[1], 0, 0, 0);
        // relu + cvt: lane now holds u[row=m][k=16*nt+4*hi+j] == A2-frag.
        h16x4 a2_0, a2_1;
#pragma unroll
        for (int r = 0; r < 4; ++r) {
            a2_0[r] = (f16)fmaxf(d0[r], 0.f);
            a2_1[r] = (f16)fmaxf(d1[r], 0.f);
        }
        f32x4 acc[4];
#pragma unroll
        for (int g = 0; g < 4; ++g) {
            f32x4 a = f32x4{cb[g], cb[g], cb[g], cb[g]};
            a = __builtin_amdgcn_mfma_f32_16x16x16f16(a2_0, b2[g][0], a, 0, 0, 0);
            a = __builtin_amdgcn_mfma_f32_16x16x16f16(a2_1, b2[g][1], a, 0, 0, 0);
            acc[g] = a;
        }
        // D2: lane holds rows 4*hi+r, col h=m. Pack (i,f) (g,o) -> 8B store.
#pragma unroll
        for (int r = 0; r < 4; ++r) {
            uint2 o;
            auto p0 = __builtin_amdgcn_cvt_pkrtz(acc[0][r], acc[1][r]);
            auto p1 = __builtin_amdgcn_cvt_pkrtz(acc[2][r], acc[3][r]);
            o.x = __builtin_bit_cast(unsigned, p0);
            o.y = __builtin_bit_cast(unsigned, p1);
            outp[(row0 + 4 * hi + r) * 16 + m] = o;
        }
    }
}

#define LSTM_STEP(Q, NI) do {                                                  \
    asm volatile("" ::: "memory");                                             \
    float4 hv0 = *(const float4*)&hbuf[e][0];                                  \
    float4 hv1 = *(const float4*)&hbuf[e][4];                                  \
    float4 hv2 = *(const float4*)&hbuf[e][8];                                  \
    float4 hv3 = *(const float4*)&hbuf[e][12];                                 \
    h16x4 qp = __builtin_bit_cast(h16x4, Q);                                   \
    float gi = (float)qp[0], gf = (float)qp[1];                                \
    float gg = (float)qp[2], go = (float)qp[3];                                \
    Q = xp[NI];                                                                \
    const float hk[16] = {hv0.x, hv0.y, hv0.z, hv0.w, hv1.x, hv1.y, hv1.z,     \
                          hv1.w, hv2.x, hv2.y, hv2.z, hv2.w, hv3.x, hv3.y,     \
                          hv3.z, hv3.w};                                       \
    _Pragma("unroll")                                                          \
    for (int k = 0; k < 16; ++k) {                                             \
        gi = fmaf(wi[k], hk[k], gi);                                           \
        gf = fmaf(wf[k], hk[k], gf);                                           \
        gg = fmaf(wg[k], hk[k], gg);                                           \
        go = fmaf(wo[k], hk[k], go);                                           \
    }                                                                          \
    float tg = tanh_fast(gg);                                                  \
    float si = sigm(gi);                                                       \
    cs = fmaf(sigm(gf), cs, si * tg);                                          \
    hs = sigm(go) * tanh_fast(cs);                                             \
    asm volatile("" ::: "memory");                                             \
    hbuf[e][h] = hs;                                                           \
} while (0)

// Consumer: 16 lanes/element, 4 elements/wave. 4-deep xg prefetch ring,
// h-broadcast via LDS (ds_read_b128 x4, broadcast within 16-lane group).
__global__ __launch_bounds__(64) void lstm_chunk(
    const uint2* __restrict__ xg,
    const float* __restrict__ Whh,
    const float* __restrict__ h_in, const float* __restrict__ c_in,
    float* __restrict__ h_st, float* __restrict__ c_st,
    const float* __restrict__ W2, const float* __restrict__ b2,
    float* __restrict__ dout,
    int Tc, int last)
{
    const int lane = threadIdx.x;
    const int h = lane & 15, e = lane >> 4;
    const int b = blockIdx.x * 4 + e;

    __shared__ __align__(64) float hbuf[4][16];

    float hs = h_in[b * 16 + h];
    float cs = c_in[b * 16 + h];

    float wi[16], wf[16], wg[16], wo[16];
    {
        const float4* W = (const float4*)Whh;
#pragma unroll
        for (int k4 = 0; k4 < 4; ++k4) {
            float4 vi = W[(h)      * 4 + k4];
            float4 vf = W[(h + 16) * 4 + k4];
            float4 vg = W[(h + 32) * 4 + k4];
            float4 vo = W[(h + 48) * 4 + k4];
            wi[4*k4]=vi.x; wi[4*k4+1]=vi.y; wi[4*k4+2]=vi.z; wi[4*k4+3]=vi.w;
            wf[4*k4]=vf.x; wf[4*k4+1]=vf.y; wf[4*k4+2]=vf.z; wf[4*k4+3]=vf.w;
            wg[4*k4]=vg.x; wg[4*k4+1]=vg.y; wg[4*k4+2]=vg.z; wg[4*k4+3]=vg.w;
            wo[4*k4]=vo.x; wo[4*k4+1]=vo.y; wo[4*k4+2]=vo.z; wo[4*k4+3]=vo.w;
        }
    }

    const uint2* xp = xg + (size_t)b * Tc * 16 + h;
    uint2 q0 = xp[0], q1 = xp[16], q2 = xp[32], q3 = xp[48];
    hbuf[e][h] = hs;

    for (int t = 0; t < Tc; t += 4) {
        LSTM_STEP(q0, (t + 4) * 16);
        LSTM_STEP(q1, (t + 5) * 16);
        LSTM_STEP(q2, (t + 6) * 16);
        LSTM_STEP(q3, (t + 7) * 16);
    }

    h_st[b * 16 + h] = hs;
    c_st[b * 16 + h] = cs;

    if (last) {
        dout[4096 + b * 16 + h]         = hs;   // hT [1,B,H]
        dout[4096 + 65536 + b * 16 + h] = cs;   // cT [1,B,H]
        float p = hs * W2[h];
        p += __shfl_xor(p, 1);
        p += __shfl_xor(p, 2);
        p += __shfl_xor(p, 4);
        p += __shfl_xor(p, 8);
        if (h == 0) dout[b] = tanh_fast(p + b2[0]);   // out [B,1]
    }
}

extern "C" void kernel_launch(void* const* d_in, const int* in_sizes, int n_in,
                              void* d_out, int out_size, void* d_ws, size_t ws_size,
                              hipStream_t stream)
{
    const float* x   = (const float*)d_in[0];
    const float* h0  = (const float*)d_in[1];
    const float* c0  = (const float*)d_in[2];
    const float* W1  = (const float*)d_in[3];
    const float* b1  = (const float*)d_in[4];
    const float* Wih = (const float*)d_in[5];
    const float* Whh = (const float*)d_in[6];
    const float* bih = (const float*)d_in[7];
    const float* bhh = (const float*)d_in[8];
    const float* W2  = (const float*)d_in[9];
    const float* b2  = (const float*)d_in[10];
    float* out = (float*)d_out;

    // Tc=128 preferred: 64MB xg chunk (L3-resident for the consumer).
    const size_t state_bytes = (size_t)2 * 65536 * 4 + 4096;
    int tcShift = 7;
    while (tcShift > 4 &&
           ((size_t)4096 * ((size_t)128 << tcShift) + state_bytes) > ws_size)
        tcShift--;
    const int Tc = 1 << tcShift;
    const size_t xg_bytes = (size_t)4096 * Tc * 128;

    uint2* xg   = (uint2*)d_ws;
    float* h_st = (float*)((char*)d_ws + xg_bytes);
    float* c_st = h_st + 65536;

    const int nchunk = 512 / Tc;
    for (int c = 0; c < nchunk; ++c) {
        const int t0 = c * Tc;
        xg_producer<<<dim3(1024), dim3(256), 0, stream>>>(
            x, W1, b1, Wih, bih, bhh, xg, t0, Tc);
        const float* hi = (c == 0) ? h0 : h_st;
        const float* ci = (c == 0) ? c0 : c_st;
        lstm_chunk<<<dim3(1024), dim3(64), 0, stream>>>(
            xg, Whh, hi, ci, h_st, c_st, W2, b2, out,
            Tc, (c == nchunk - 1) ? 1 : 0);
    }
}

// Round 4
// 147.672 us; speedup vs baseline: 3.1912x; 1.5136x over previous
//
#include <hip/hip_runtime.h>

typedef __fp16 f16;
typedef __attribute__((ext_vector_type(4))) __fp16 h16x4;
typedef __attribute__((ext_vector_type(4))) float f32x4;

__device__ __forceinline__ float sigm(float x) {
    return __builtin_amdgcn_rcpf(1.0f + __expf(-x));
}
__device__ __forceinline__ float tanh_fast(float x) {
    // tanh(x) = 1 - 2/(1+e^{2x}); stable at both tails
    return 1.0f - 2.0f * __builtin_amdgcn_rcpf(1.0f + __expf(2.0f * x));
}
__device__ __forceinline__ h16x4 cvt4(float4 v) {
    h16x4 r; r[0] = (f16)v.x; r[1] = (f16)v.y; r[2] = (f16)v.z; r[3] = (f16)v.w;
    return r;
}
// pack 4 floats -> h16x4 via 2x cvt_pkrtz
__device__ __forceinline__ h16x4 pack4(float a, float b, float c, float d) {
    auto p0 = __builtin_amdgcn_cvt_pkrtz(a, b);
    auto p1 = __builtin_amdgcn_cvt_pkrtz(c, d);
    uint2 u = make_uint2(__builtin_bit_cast(unsigned, p0),
                         __builtin_bit_cast(unsigned, p1));
    return __builtin_bit_cast(h16x4, u);
}
// select element q (runtime, lane-varying) of an f32x4 via 3 cndmask
__device__ __forceinline__ float sel4(f32x4 v, bool q1, bool q2) {
    float a = q1 ? v[1] : v[0];
    float b = q1 ? v[3] : v[2];
    return q2 ? b : a;
}

// Fully fused ReflexNet: fc1+ReLU+gate-GEMM generated per 16-step tile via
// MFMA into LDS (double-buffered); LSTM recurrence as 4x mfma_16x16x16_f16
// per step (gates^T = Whh @ h^T), h stays in-register (B-frag == activated
// D-frag after a 4-wide shfl gather). 1 wave/block, 4 batch elems/block.
__global__ __launch_bounds__(64) void reflex_fused(
    const float* __restrict__ x,
    const float* __restrict__ h0, const float* __restrict__ c0,
    const float* __restrict__ W1, const float* __restrict__ b1,
    const float* __restrict__ Wih, const float* __restrict__ Whh,
    const float* __restrict__ bih, const float* __restrict__ bhh,
    const float* __restrict__ W2, const float* __restrict__ b2,
    float* __restrict__ dout)
{
    const int lane = threadIdx.x;
    const int m = lane & 15, hi = lane >> 4;
    const int e = m & 3, q = m >> 2;        // elem-in-block, replica/row index
    const int b0 = blockIdx.x << 2;
    const int b = b0 + e;
    const bool q1 = (q & 1) != 0, q2 = (q & 2) != 0;

    // xg tile double-buffer: [2][16 t][4 G][4 hi][4 e] of f32x4 = 32 KB
    __shared__ f32x4 xgl[2][16][4][4][4];

    // ---- weight fragments (all mappings verified in R3) ----
    // GEMM1 (u^T = W1 @ x^T): A1[m][k=4hi+j], C-init = b1 rows
    h16x4 a1[2]; f32x4 c1[2];
#pragma unroll
    for (int nt = 0; nt < 2; ++nt) {
        float4 wv = make_float4(0.f, 0.f, 0.f, 0.f);
        if (hi < 3) wv = *(const float4*)(W1 + (nt * 16 + m) * 12 + 4 * hi);
        a1[nt] = cvt4(wv);
        float4 bv = *(const float4*)(b1 + nt * 16 + 4 * hi);
        c1[nt] = f32x4{bv.x, bv.y, bv.z, bv.w};
    }
    // GEMM2 (xg^T = Wih @ u^T): A2 blocks; C-init = bih+bhh rows
    // Rec  (gates^T = Whh @ h^T): A blocks ar[G]
    h16x4 a2[4][2]; f32x4 cb[4]; h16x4 ar[4];
#pragma unroll
    for (int G = 0; G < 4; ++G) {
        const int gr = G * 16 + m;
#pragma unroll
        for (int s = 0; s < 2; ++s)
            a2[G][s] = cvt4(*(const float4*)(Wih + gr * 32 + s * 16 + 4 * hi));
        ar[G] = cvt4(*(const float4*)(Whh + gr * 16 + 4 * hi));
        float4 bi = *(const float4*)(bih + G * 16 + 4 * hi);
        float4 bh = *(const float4*)(bhh + G * 16 + 4 * hi);
        cb[G] = f32x4{bi.x + bh.x, bi.y + bh.y, bi.z + bh.z, bi.w + bh.w};
    }

    // ---- state ----
    h16x4 hf = cvt4(*(const float4*)(h0 + b * 16 + 4 * hi));  // B-frag of h
    float cs = c0[b * 16 + 4 * hi + q];   // lane owns (elem e, h = 4hi+q)
    float hn = 0.f;
    const int gsl = lane & 51;            // shfl gather base (clear q bits)

    const float* xrow = x + (size_t)b * 512 * 12 + 4 * hi;
    float4 bxp[4];

#define LOADX(TILE) do {                                                       \
    _Pragma("unroll")                                                          \
    for (int c_ = 0; c_ < 4; ++c_) {                                           \
        if (hi < 3)                                                            \
            bxp[c_] = *(const float4*)(xrow + (size_t)((TILE)*16 + c_*4 + q)*12);\
        else bxp[c_] = make_float4(0.f, 0.f, 0.f, 0.f);                        \
    } } while (0)

#define GEN(NB) do {                                                           \
    f32x4* wb = &xgl[NB][0][0][0][0];                                          \
    _Pragma("unroll")                                                          \
    for (int c_ = 0; c_ < 4; ++c_) {                                           \
        h16x4 bx = cvt4(bxp[c_]);                                              \
        f32x4 d0 = __builtin_amdgcn_mfma_f32_16x16x16f16(a1[0], bx, c1[0],0,0,0);\
        f32x4 d1 = __builtin_amdgcn_mfma_f32_16x16x16f16(a1[1], bx, c1[1],0,0,0);\
        h16x4 u0 = pack4(fmaxf(d0[0],0.f), fmaxf(d0[1],0.f),                   \
                         fmaxf(d0[2],0.f), fmaxf(d0[3],0.f));                  \
        h16x4 u1 = pack4(fmaxf(d1[0],0.f), fmaxf(d1[1],0.f),                   \
                         fmaxf(d1[2],0.f), fmaxf(d1[3],0.f));                  \
        const int toff = c_ * 4 + q;                                           \
        _Pragma("unroll")                                                      \
        for (int G_ = 0; G_ < 4; ++G_) {                                       \
            f32x4 acc = cb[G_];                                                \
            acc = __builtin_amdgcn_mfma_f32_16x16x16f16(a2[G_][0], u0, acc,0,0,0);\
            acc = __builtin_amdgcn_mfma_f32_16x16x16f16(a2[G_][1], u1, acc,0,0,0);\
            wb[(toff * 4 + G_) * 16 + hi * 4 + e] = acc;                       \
        } } } while (0)

#define STEP(RB, TT) do {                                                      \
    f32x4 gi4 = (RB)[(TT)*64 +  0 + hi*4 + e];                                 \
    f32x4 gf4 = (RB)[(TT)*64 + 16 + hi*4 + e];                                 \
    f32x4 gg4 = (RB)[(TT)*64 + 32 + hi*4 + e];                                 \
    f32x4 go4 = (RB)[(TT)*64 + 48 + hi*4 + e];                                 \
    gi4 = __builtin_amdgcn_mfma_f32_16x16x16f16(ar[0], hf, gi4, 0, 0, 0);      \
    gf4 = __builtin_amdgcn_mfma_f32_16x16x16f16(ar[1], hf, gf4, 0, 0, 0);      \
    gg4 = __builtin_amdgcn_mfma_f32_16x16x16f16(ar[2], hf, gg4, 0, 0, 0);      \
    go4 = __builtin_amdgcn_mfma_f32_16x16x16f16(ar[3], hf, go4, 0, 0, 0);      \
    float gi = sel4(gi4, q1, q2), gf = sel4(gf4, q1, q2);                      \
    float gg = sel4(gg4, q1, q2), go = sel4(go4, q1, q2);                      \
    float tg = tanh_fast(gg);                                                  \
    cs = fmaf(sigm(gf), cs, sigm(gi) * tg);                                    \
    hn = sigm(go) * tanh_fast(cs);                                             \
    float j0 = __shfl(hn, gsl),     j1 = __shfl(hn, gsl | 4);                  \
    float j2 = __shfl(hn, gsl | 8), j3 = __shfl(hn, gsl | 12);                 \
    hf = pack4(j0, j1, j2, j3);                                                \
} while (0)

    LOADX(0);
    GEN(0);
    LOADX(1);

    for (int tile = 0; tile < 32; ++tile) {
        const int cur = tile & 1;
        if (tile < 31) {
            GEN(cur ^ 1);
            if (tile < 30) LOADX(tile + 2);
        }
        const f32x4* rb = &xgl[cur][0][0][0][0];
#pragma unroll
        for (int tt = 0; tt < 16; ++tt) STEP(rb, tt);
    }

    // ---- outputs ----
    dout[4096 + b * 16 + 4 * hi + q]         = hn;   // hT [1,B,H]
    dout[4096 + 65536 + b * 16 + 4 * hi + q] = cs;   // cT [1,B,H]
    float p = hn * W2[4 * hi + q];
    p += __shfl_xor(p, 4);
    p += __shfl_xor(p, 8);
    p += __shfl_xor(p, 16);
    p += __shfl_xor(p, 32);
    if (lane < 4) dout[b0 + lane] = tanh_fast(p + b2[0]);   // out [B,1]

#undef LOADX
#undef GEN
#undef STEP
}

extern "C" void kernel_launch(void* const* d_in, const int* in_sizes, int n_in,
                              void* d_out, int out_size, void* d_ws, size_t ws_size,
                              hipStream_t stream)
{
    const float* x   = (const float*)d_in[0];
    const float* h0  = (const float*)d_in[1];
    const float* c0  = (const float*)d_in[2];
    const float* W1  = (const float*)d_in[3];
    const float* b1  = (const float*)d_in[4];
    const float* Wih = (const float*)d_in[5];
    const float* Whh = (const float*)d_in[6];
    const float* bih = (const float*)d_in[7];
    const float* bhh = (const float*)d_in[8];
    const float* W2  = (const float*)d_in[9];
    const float* b2  = (const float*)d_in[10];
    float* out = (float*)d_out;

    reflex_fused<<<dim3(1024), dim3(64), 0, stream>>>(
        x, h0, c0, W1, b1, Wih, Whh, bih, bhh, W2, b2, out);
}

// Round 5
// 143.622 us; speedup vs baseline: 3.2812x; 1.0282x over previous
//
#include <hip/hip_runtime.h>

typedef __fp16 f16;
typedef __attribute__((ext_vector_type(4))) __fp16 h16x4;
typedef __attribute__((ext_vector_type(4))) float f32x4;

__device__ __forceinline__ float sigm(float x) {
    return __builtin_amdgcn_rcpf(1.0f + __expf(-x));
}
__device__ __forceinline__ float tanh_fast(float x) {
    return 1.0f - 2.0f * __builtin_amdgcn_rcpf(1.0f + __expf(2.0f * x));
}
__device__ __forceinline__ h16x4 cvt4(float4 v) {
    h16x4 r; r[0] = (f16)v.x; r[1] = (f16)v.y; r[2] = (f16)v.z; r[3] = (f16)v.w;
    return r;
}
__device__ __forceinline__ h16x4 pack4(float a, float b, float c, float d) {
    auto p0 = __builtin_amdgcn_cvt_pkrtz(a, b);
    auto p1 = __builtin_amdgcn_cvt_pkrtz(c, d);
    uint2 u = make_uint2(__builtin_bit_cast(unsigned, p0),
                         __builtin_bit_cast(unsigned, p1));
    return __builtin_bit_cast(h16x4, u);
}
__device__ __forceinline__ float sel4(f32x4 v, bool q1, bool q2) {
    float a = q1 ? v[1] : v[0];
    float b = q1 ? v[3] : v[2];
    return q2 ? b : a;
}

// Fully fused: GEN (fc1+relu+gate GEMM via MFMA, f16-packed into LDS) is
// interleaved slice-wise between recurrence STEPs; recurrence = 4x
// mfma_16x16x16_f16 with bias in C; gates read as one ds_read_b64/step
// (2-deep register prefetch ring); h-gather via 4 raw ds_bpermute.
__global__ __launch_bounds__(64) void reflex_fused(
    const float* __restrict__ x,
    const float* __restrict__ h0, const float* __restrict__ c0,
    const float* __restrict__ W1, const float* __restrict__ b1,
    const float* __restrict__ Wih, const float* __restrict__ Whh,
    const float* __restrict__ bih, const float* __restrict__ bhh,
    const float* __restrict__ W2, const float* __restrict__ b2,
    float* __restrict__ dout)
{
    const int lane = threadIdx.x;
    const int m = lane & 15, hi = lane >> 4;
    const int e = m & 3, q = m >> 2;
    const int b0 = blockIdx.x << 2;
    const int b = b0 + e;
    const bool q1 = (q & 1) != 0, q2 = (q & 2) != 0;

    // gate tile double-buffer: [2][16 t][16 h][4 e] uint2 (f16 i,f,g,o) = 16 KB
    __shared__ uint2 xgl[2][1024];

    // ---- weight fragments (mappings HW-verified in R3/R4) ----
    h16x4 a1[2]; f32x4 c1[2];
#pragma unroll
    for (int nt = 0; nt < 2; ++nt) {
        float4 wv = make_float4(0.f, 0.f, 0.f, 0.f);
        if (hi < 3) wv = *(const float4*)(W1 + (nt * 16 + m) * 12 + 4 * hi);
        a1[nt] = cvt4(wv);
        float4 bv = *(const float4*)(b1 + nt * 16 + 4 * hi);
        c1[nt] = f32x4{bv.x, bv.y, bv.z, bv.w};
    }
    h16x4 a2[4][2]; f32x4 cb[4]; h16x4 ar[4];
#pragma unroll
    for (int G = 0; G < 4; ++G) {
        const int gr = G * 16 + m;
#pragma unroll
        for (int s = 0; s < 2; ++s)
            a2[G][s] = cvt4(*(const float4*)(Wih + gr * 32 + s * 16 + 4 * hi));
        ar[G] = cvt4(*(const float4*)(Whh + gr * 16 + 4 * hi));
        float4 bi = *(const float4*)(bih + G * 16 + 4 * hi);
        float4 bh = *(const float4*)(bhh + G * 16 + 4 * hi);
        cb[G] = f32x4{bi.x + bh.x, bi.y + bh.y, bi.z + bh.z, bi.w + bh.w};
    }

    // ---- state ----
    h16x4 hf = cvt4(*(const float4*)(h0 + b * 16 + 4 * hi));
    float cs = c0[b * 16 + 4 * hi + q];
    float hn = 0.f;

    // consumer gate-read slot bases: va[j] for t with t&3==j
    int va[4];
#pragma unroll
    for (int j = 0; j < 4; ++j) va[j] = hi * 16 + ((q ^ hi ^ j) << 2) + e;
    // bpermute byte-indices: source lanes (hi*16 + 4j + e)
    const int gsl = lane & 51;
    const int bp0 = gsl << 2, bp1 = (gsl | 4) << 2;
    const int bp2 = (gsl | 8) << 2, bp3 = (gsl | 12) << 2;
    // producer store bases
    const int psA = q * 64 + hi * 16 + e;   // + C*256 + (psB ^ (r<<2))
    const int psB = (hi ^ q) << 2;

    const float* xrow = x + (size_t)b * 512 * 12 + 4 * hi;
    float4 bxp;

#define LOADXROW(ROW) do {                                                     \
    int r_ = (ROW) < 511 ? (ROW) : 511;                                        \
    if (hi < 3) bxp = *(const float4*)(xrow + r_ * 12);                        \
} while (0)

#define GENSLICE(DST, CC) do {                                                 \
    h16x4 bx = {0, 0, 0, 0};                                                   \
    if (hi < 3) bx = cvt4(bxp);                                                \
    f32x4 d0 = __builtin_amdgcn_mfma_f32_16x16x16f16(a1[0], bx, c1[0],0,0,0);  \
    f32x4 d1 = __builtin_amdgcn_mfma_f32_16x16x16f16(a1[1], bx, c1[1],0,0,0);  \
    h16x4 u0 = pack4(fmaxf(d0[0],0.f), fmaxf(d0[1],0.f),                       \
                     fmaxf(d0[2],0.f), fmaxf(d0[3],0.f));                      \
    h16x4 u1 = pack4(fmaxf(d1[0],0.f), fmaxf(d1[1],0.f),                       \
                     fmaxf(d1[2],0.f), fmaxf(d1[3],0.f));                      \
    f32x4 z4 = {0.f, 0.f, 0.f, 0.f};                                           \
    f32x4 A0 = __builtin_amdgcn_mfma_f32_16x16x16f16(a2[0][0], u0, z4,0,0,0);  \
    f32x4 A1 = __builtin_amdgcn_mfma_f32_16x16x16f16(a2[1][0], u0, z4,0,0,0);  \
    f32x4 A2 = __builtin_amdgcn_mfma_f32_16x16x16f16(a2[2][0], u0, z4,0,0,0);  \
    f32x4 A3 = __builtin_amdgcn_mfma_f32_16x16x16f16(a2[3][0], u0, z4,0,0,0);  \
    A0 = __builtin_amdgcn_mfma_f32_16x16x16f16(a2[0][1], u1, A0, 0, 0, 0);     \
    A1 = __builtin_amdgcn_mfma_f32_16x16x16f16(a2[1][1], u1, A1, 0, 0, 0);     \
    A2 = __builtin_amdgcn_mfma_f32_16x16x16f16(a2[2][1], u1, A2, 0, 0, 0);     \
    A3 = __builtin_amdgcn_mfma_f32_16x16x16f16(a2[3][1], u1, A3, 0, 0, 0);     \
    _Pragma("unroll")                                                          \
    for (int r_ = 0; r_ < 4; ++r_) {                                           \
        uint2 w_;                                                              \
        auto w0 = __builtin_amdgcn_cvt_pkrtz(A0[r_], A1[r_]);                  \
        auto w1 = __builtin_amdgcn_cvt_pkrtz(A2[r_], A3[r_]);                  \
        w_.x = __builtin_bit_cast(unsigned, w0);                               \
        w_.y = __builtin_bit_cast(unsigned, w1);                               \
        (DST)[psA + (CC) * 256 + (psB ^ (r_ << 2))] = w_;                      \
    }                                                                          \
} while (0)

#define STEP(TT, QC) do {                                                      \
    f32x4 di = __builtin_amdgcn_mfma_f32_16x16x16f16(ar[0], hf, cb[0],0,0,0);  \
    f32x4 df = __builtin_amdgcn_mfma_f32_16x16x16f16(ar[1], hf, cb[1],0,0,0);  \
    f32x4 dg = __builtin_amdgcn_mfma_f32_16x16x16f16(ar[2], hf, cb[2],0,0,0);  \
    f32x4 dq = __builtin_amdgcn_mfma_f32_16x16x16f16(ar[3], hf, cb[3],0,0,0);  \
    h16x4 gx = __builtin_bit_cast(h16x4, QC);                                  \
    { const uint2* pb_ = ((TT) + 2 < 16) ? bcur : bnext;                       \
      QC = pb_[(((TT) + 2) & 15) * 64 + va[((TT) + 2) & 3]]; }                 \
    float gi = sel4(di, q1, q2) + (float)gx[0];                                \
    float gf = sel4(df, q1, q2) + (float)gx[1];                                \
    float gg = sel4(dg, q1, q2) + (float)gx[2];                                \
    float go = sel4(dq, q1, q2) + (float)gx[3];                                \
    float tg = tanh_fast(gg);                                                  \
    cs = fmaf(sigm(gf), cs, sigm(gi) * tg);                                    \
    hn = sigm(go) * tanh_fast(cs);                                             \
    int hnb = __builtin_bit_cast(int, hn);                                     \
    float j0 = __builtin_bit_cast(float, __builtin_amdgcn_ds_bpermute(bp0, hnb)); \
    float j1 = __builtin_bit_cast(float, __builtin_amdgcn_ds_bpermute(bp1, hnb)); \
    float j2 = __builtin_bit_cast(float, __builtin_amdgcn_ds_bpermute(bp2, hnb)); \
    float j3 = __builtin_bit_cast(float, __builtin_amdgcn_ds_bpermute(bp3, hnb)); \
    hf = pack4(j0, j1, j2, j3);                                                \
} while (0)

    // ---- prologue: GEN full tile 0 into buffer 0, preload next x row ----
#pragma unroll
    for (int C = 0; C < 4; ++C) {
        LOADXROW(C * 4 + q);
        GENSLICE(&xgl[0][0], C);
    }
    LOADXROW(16 + q);   // tile 1, slice 0

    for (int tile = 0; tile < 32; ++tile) {
        const uint2* bcur = &xgl[tile & 1][0];
        uint2* bnw = &xgl[(tile & 1) ^ 1][0];
        const uint2* bnext = bnw;
        const bool more = tile < 31;
        const int nrow = (tile + 1) * 16;

        uint2 qA = bcur[0 * 64 + va[0]];
        uint2 qB = bcur[1 * 64 + va[1]];

        STEP(0, qA);
        STEP(1, qB);
        if (more) GENSLICE(bnw, 0);
        LOADXROW(nrow + 4 + q);
        STEP(2, qA);
        STEP(3, qB);
        STEP(4, qA);
        STEP(5, qB);
        if (more) GENSLICE(bnw, 1);
        LOADXROW(nrow + 8 + q);
        STEP(6, qA);
        STEP(7, qB);
        STEP(8, qA);
        STEP(9, qB);
        if (more) GENSLICE(bnw, 2);
        LOADXROW(nrow + 12 + q);
        STEP(10, qA);
        STEP(11, qB);
        STEP(12, qA);
        STEP(13, qB);
        if (more) GENSLICE(bnw, 3);
        LOADXROW(nrow + 16 + q);
        STEP(14, qA);
        STEP(15, qB);
    }

    // ---- outputs ----
    dout[4096 + b * 16 + 4 * hi + q]         = hn;   // hT [1,B,H]
    dout[4096 + 65536 + b * 16 + 4 * hi + q] = cs;   // cT [1,B,H]
    float p = hn * W2[4 * hi + q];
    p += __shfl_xor(p, 4);
    p += __shfl_xor(p, 8);
    p += __shfl_xor(p, 16);
    p += __shfl_xor(p, 32);
    if (lane < 4) dout[b0 + lane] = tanh_fast(p + b2[0]);   // out [B,1]

#undef LOADXROW
#undef GENSLICE
#undef STEP
}

extern "C" void kernel_launch(void* const* d_in, const int* in_sizes, int n_in,
                              void* d_out, int out_size, void* d_ws, size_t ws_size,
                              hipStream_t stream)
{
    const float* x   = (const float*)d_in[0];
    const float* h0  = (const float*)d_in[1];
    const float* c0  = (const float*)d_in[2];
    const float* W1  = (const float*)d_in[3];
    const float* b1  = (const float*)d_in[4];
    const float* Wih = (const float*)d_in[5];
    const float* Whh = (const float*)d_in[6];
    const float* bih = (const float*)d_in[7];
    const float* bhh = (const float*)d_in[8];
    const float* W2  = (const float*)d_in[9];
    const float* b2  = (const float*)d_in[10];
    float* out = (float*)d_out;

    reflex_fused<<<dim3(1024), dim3(64), 0, stream>>>(
        x, h0, c0, W1, b1, Wih, Whh, bih, bhh, W2, b2, out);
}

// Round 6
// 114.880 us; speedup vs baseline: 4.1021x; 1.2502x over previous
//
#include <hip/hip_runtime.h>

typedef __fp16 f16;
typedef __attribute__((ext_vector_type(4))) __fp16 h16x4;
typedef __attribute__((ext_vector_type(4))) float f32x4;

__device__ __forceinline__ float sigm(float x) {
    return __builtin_amdgcn_rcpf(1.0f + __expf(-x));
}
__device__ __forceinline__ float tanh_fast(float x) {
    return 1.0f - 2.0f * __builtin_amdgcn_rcpf(1.0f + __expf(2.0f * x));
}
__device__ __forceinline__ h16x4 cvt4(float4 v) {
    h16x4 r; r[0] = (f16)v.x; r[1] = (f16)v.y; r[2] = (f16)v.z; r[3] = (f16)v.w;
    return r;
}
__device__ __forceinline__ h16x4 pack4(float a, float b, float c, float d) {
    auto p0 = __builtin_amdgcn_cvt_pkrtz(a, b);
    auto p1 = __builtin_amdgcn_cvt_pkrtz(c, d);
    uint2 u = make_uint2(__builtin_bit_cast(unsigned, p0),
                         __builtin_bit_cast(unsigned, p1));
    return __builtin_bit_cast(h16x4, u);
}
__device__ __forceinline__ float sel4(f32x4 v, bool q1, bool q2) {
    float a = q1 ? v[1] : v[0];
    float b = q1 ? v[3] : v[2];
    return q2 ? b : a;
}

// Producer/consumer wave specialization. Wave1 (producer): fc1+relu+gate
// GEMM via MFMA for all 32 tiles (16 steps each) into double-buffered LDS;
// owns ALL global x loads. Wave0 (consumer): pure LSTM recurrence — 4x
// mfma_16x16x16_f16 (bias in C), 1 ds_read_b64 gate fetch/step (2-deep,
// statically guarded), activations, 4x ds_bpermute h-gather. One
// __syncthreads per tile. Math identical to R5 (absmax must not change).
__global__ __launch_bounds__(128) void reflex_fused(
    const float* __restrict__ x,
    const float* __restrict__ h0, const float* __restrict__ c0,
    const float* __restrict__ W1, const float* __restrict__ b1,
    const float* __restrict__ Wih, const float* __restrict__ Whh,
    const float* __restrict__ bih, const float* __restrict__ bhh,
    const float* __restrict__ W2, const float* __restrict__ b2,
    float* __restrict__ dout)
{
    const int tid = threadIdx.x;
    const int lane = tid & 63;
    const int m = lane & 15, hi = lane >> 4;
    const int e = m & 3, q = m >> 2;
    const int b0 = blockIdx.x << 2;
    const int b = b0 + e;

    // gate tile double-buffer: [2][16 t][16 h][4 e] uint2 (f16 i,f,g,o) = 16 KB
    __shared__ uint2 xgl[2][1024];

    if (tid >= 64) {
        // ---------------- producer wave ----------------
        h16x4 a1[2]; f32x4 c1[2];
#pragma unroll
        for (int nt = 0; nt < 2; ++nt) {
            float4 wv = make_float4(0.f, 0.f, 0.f, 0.f);
            if (hi < 3) wv = *(const float4*)(W1 + (nt * 16 + m) * 12 + 4 * hi);
            a1[nt] = cvt4(wv);
            float4 bv = *(const float4*)(b1 + nt * 16 + 4 * hi);
            c1[nt] = f32x4{bv.x, bv.y, bv.z, bv.w};
        }
        h16x4 a2[4][2];
#pragma unroll
        for (int G = 0; G < 4; ++G) {
            const int gr = G * 16 + m;
#pragma unroll
            for (int s = 0; s < 2; ++s)
                a2[G][s] = cvt4(*(const float4*)(Wih + gr * 32 + s * 16 + 4 * hi));
        }
        const int psA = q * 64 + hi * 16 + e;
        const int psB = (hi ^ q) << 2;
        const float* xrow = x + (size_t)b * 512 * 12 + 4 * hi;

        for (int F = 0; F < 32; ++F) {
            float4 bxp[4];
#pragma unroll
            for (int C = 0; C < 4; ++C)
                if (hi < 3)
                    bxp[C] = *(const float4*)(xrow + (F * 16 + C * 4 + q) * 12);
            uint2* wb = &xgl[F & 1][0];
#pragma unroll
            for (int C = 0; C < 4; ++C) {
                h16x4 bx = {0, 0, 0, 0};
                if (hi < 3) bx = cvt4(bxp[C]);
                f32x4 d0 = __builtin_amdgcn_mfma_f32_16x16x16f16(a1[0], bx, c1[0], 0, 0, 0);
                f32x4 d1 = __builtin_amdgcn_mfma_f32_16x16x16f16(a1[1], bx, c1[1], 0, 0, 0);
                h16x4 u0 = pack4(fmaxf(d0[0], 0.f), fmaxf(d0[1], 0.f),
                                 fmaxf(d0[2], 0.f), fmaxf(d0[3], 0.f));
                h16x4 u1 = pack4(fmaxf(d1[0], 0.f), fmaxf(d1[1], 0.f),
                                 fmaxf(d1[2], 0.f), fmaxf(d1[3], 0.f));
                f32x4 z4 = {0.f, 0.f, 0.f, 0.f};
                f32x4 A0 = __builtin_amdgcn_mfma_f32_16x16x16f16(a2[0][0], u0, z4, 0, 0, 0);
                f32x4 A1 = __builtin_amdgcn_mfma_f32_16x16x16f16(a2[1][0], u0, z4, 0, 0, 0);
                f32x4 A2 = __builtin_amdgcn_mfma_f32_16x16x16f16(a2[2][0], u0, z4, 0, 0, 0);
                f32x4 A3 = __builtin_amdgcn_mfma_f32_16x16x16f16(a2[3][0], u0, z4, 0, 0, 0);
                A0 = __builtin_amdgcn_mfma_f32_16x16x16f16(a2[0][1], u1, A0, 0, 0, 0);
                A1 = __builtin_amdgcn_mfma_f32_16x16x16f16(a2[1][1], u1, A1, 0, 0, 0);
                A2 = __builtin_amdgcn_mfma_f32_16x16x16f16(a2[2][1], u1, A2, 0, 0, 0);
                A3 = __builtin_amdgcn_mfma_f32_16x16x16f16(a2[3][1], u1, A3, 0, 0, 0);
#pragma unroll
                for (int r = 0; r < 4; ++r) {
                    uint2 w_;
                    auto w0 = __builtin_amdgcn_cvt_pkrtz(A0[r], A1[r]);
                    auto w1 = __builtin_amdgcn_cvt_pkrtz(A2[r], A3[r]);
                    w_.x = __builtin_bit_cast(unsigned, w0);
                    w_.y = __builtin_bit_cast(unsigned, w1);
                    wb[psA + C * 256 + (psB ^ (r << 2))] = w_;
                }
            }
            __syncthreads();
        }
    } else {
        // ---------------- consumer wave ----------------
        const bool q1 = (q & 1) != 0, q2 = (q & 2) != 0;
        h16x4 ar[4]; f32x4 cb[4];
#pragma unroll
        for (int G = 0; G < 4; ++G) {
            const int gr = G * 16 + m;
            ar[G] = cvt4(*(const float4*)(Whh + gr * 16 + 4 * hi));
            float4 bi = *(const float4*)(bih + G * 16 + 4 * hi);
            float4 bh = *(const float4*)(bhh + G * 16 + 4 * hi);
            cb[G] = f32x4{bi.x + bh.x, bi.y + bh.y, bi.z + bh.z, bi.w + bh.w};
        }
        h16x4 hf = cvt4(*(const float4*)(h0 + b * 16 + 4 * hi));
        float cs = c0[b * 16 + 4 * hi + q];
        float hn = 0.f;
        int va[4];
#pragma unroll
        for (int j = 0; j < 4; ++j) va[j] = hi * 16 + ((q ^ hi ^ j) << 2) + e;
        const int gsl = lane & 51;
        const int bp0 = gsl << 2, bp1 = (gsl | 4) << 2;
        const int bp2 = (gsl | 8) << 2, bp3 = (gsl | 12) << 2;

#define STEP(TT, QC) do {                                                      \
    f32x4 di = __builtin_amdgcn_mfma_f32_16x16x16f16(ar[0], hf, cb[0],0,0,0);  \
    f32x4 df = __builtin_amdgcn_mfma_f32_16x16x16f16(ar[1], hf, cb[1],0,0,0);  \
    f32x4 dg = __builtin_amdgcn_mfma_f32_16x16x16f16(ar[2], hf, cb[2],0,0,0);  \
    f32x4 dq = __builtin_amdgcn_mfma_f32_16x16x16f16(ar[3], hf, cb[3],0,0,0);  \
    h16x4 gx = __builtin_bit_cast(h16x4, QC);                                  \
    if ((TT) < 14) QC = bcur[((TT) + 2) * 64 + va[((TT) + 2) & 3]];            \
    float gg = sel4(dg, q1, q2) + (float)gx[2];                                \
    float gi = sel4(di, q1, q2) + (float)gx[0];                                \
    float gf = sel4(df, q1, q2) + (float)gx[1];                                \
    float go = sel4(dq, q1, q2) + (float)gx[3];                                \
    float tg = tanh_fast(gg);                                                  \
    cs = fmaf(sigm(gf), cs, sigm(gi) * tg);                                    \
    hn = sigm(go) * tanh_fast(cs);                                             \
    int hnb = __builtin_bit_cast(int, hn);                                     \
    float j0 = __builtin_bit_cast(float, __builtin_amdgcn_ds_bpermute(bp0, hnb)); \
    float j1 = __builtin_bit_cast(float, __builtin_amdgcn_ds_bpermute(bp1, hnb)); \
    float j2 = __builtin_bit_cast(float, __builtin_amdgcn_ds_bpermute(bp2, hnb)); \
    float j3 = __builtin_bit_cast(float, __builtin_amdgcn_ds_bpermute(bp3, hnb)); \
    hf = pack4(j0, j1, j2, j3);                                                \
} while (0)

        __builtin_amdgcn_s_setprio(1);
        for (int T = 0; T < 32; ++T) {
            __syncthreads();
            const uint2* bcur = &xgl[T & 1][0];
            uint2 qA = bcur[va[0]];
            uint2 qB = bcur[64 + va[1]];
            STEP(0, qA);  STEP(1, qB);
            STEP(2, qA);  STEP(3, qB);
            STEP(4, qA);  STEP(5, qB);
            STEP(6, qA);  STEP(7, qB);
            STEP(8, qA);  STEP(9, qB);
            STEP(10, qA); STEP(11, qB);
            STEP(12, qA); STEP(13, qB);
            STEP(14, qA); STEP(15, qB);
        }
        __builtin_amdgcn_s_setprio(0);
#undef STEP

        // ---- outputs ----
        dout[4096 + b * 16 + 4 * hi + q]         = hn;   // hT [1,B,H]
        dout[4096 + 65536 + b * 16 + 4 * hi + q] = cs;   // cT [1,B,H]
        float p = hn * W2[4 * hi + q];
        p += __shfl_xor(p, 4);
        p += __shfl_xor(p, 8);
        p += __shfl_xor(p, 16);
        p += __shfl_xor(p, 32);
        if (lane < 4) dout[b0 + lane] = tanh_fast(p + b2[0]);   // out [B,1]
    }
}

extern "C" void kernel_launch(void* const* d_in, const int* in_sizes, int n_in,
                              void* d_out, int out_size, void* d_ws, size_t ws_size,
                              hipStream_t stream)
{
    const float* x   = (const float*)d_in[0];
    const float* h0  = (const float*)d_in[1];
    const float* c0  = (const float*)d_in[2];
    const float* W1  = (const float*)d_in[3];
    const float* b1  = (const float*)d_in[4];
    const float* Wih = (const float*)d_in[5];
    const float* Whh = (const float*)d_in[6];
    const float* bih = (const float*)d_in[7];
    const float* bhh = (const float*)d_in[8];
    const float* W2  = (const float*)d_in[9];
    const float* b2  = (const float*)d_in[10];
    float* out = (float*)d_out;

    reflex_fused<<<dim3(1024), dim3(128), 0, stream>>>(
        x, h0, c0, W1, b1, Wih, Whh, bih, bhh, W2, b2, out);
}

// Round 7
// 102.159 us; speedup vs baseline: 4.6129x; 1.1245x over previous
//
#include <hip/hip_runtime.h>

typedef __fp16 f16;
typedef __attribute__((ext_vector_type(4))) __fp16 h16x4;
typedef __attribute__((ext_vector_type(4))) float f32x4;

__device__ __forceinline__ float sigm(float x) {
    return __builtin_amdgcn_rcpf(1.0f + __expf(-x));
}
__device__ __forceinline__ float tanh_fast(float x) {
    return 1.0f - 2.0f * __builtin_amdgcn_rcpf(1.0f + __expf(2.0f * x));
}
__device__ __forceinline__ h16x4 cvt4(float4 v) {
    h16x4 r; r[0] = (f16)v.x; r[1] = (f16)v.y; r[2] = (f16)v.z; r[3] = (f16)v.w;
    return r;
}
__device__ __forceinline__ h16x4 pack4(float a, float b, float c, float d) {
    auto p0 = __builtin_amdgcn_cvt_pkrtz(a, b);
    auto p1 = __builtin_amdgcn_cvt_pkrtz(c, d);
    uint2 u = make_uint2(__builtin_bit_cast(unsigned, p0),
                         __builtin_bit_cast(unsigned, p1));
    return __builtin_bit_cast(h16x4, u);
}
__device__ __forceinline__ float sel4(f32x4 v, bool q1, bool q2) {
    float a = q1 ? v[1] : v[0];
    float b = q1 ? v[3] : v[2];
    return q2 ? b : a;
}

// Producer/consumer wave specialization (R6 structure). Consumer column
// mapping changed to e=m>>2, q=m&3 so the h-gather group is a CONSECUTIVE
// QUAD -> 4x v_mov_dpp quad_perm broadcasts (~8 cyc) replace 4x
// ds_bpermute (~120 cyc LDS latency) on the serial chain. Producer is
// unchanged; LDS slot algebra re-derived to match (r = q_c). Math
// identical to R5/R6 -> absmax must stay exactly 1.953125e-3.
__global__ __launch_bounds__(128) void reflex_fused(
    const float* __restrict__ x,
    const float* __restrict__ h0, const float* __restrict__ c0,
    const float* __restrict__ W1, const float* __restrict__ b1,
    const float* __restrict__ Wih, const float* __restrict__ Whh,
    const float* __restrict__ bih, const float* __restrict__ bhh,
    const float* __restrict__ W2, const float* __restrict__ b2,
    float* __restrict__ dout)
{
    const int tid = threadIdx.x;
    const int lane = tid & 63;
    const int m = lane & 15, hi = lane >> 4;
    const int b0 = blockIdx.x << 2;

    // gate tile double-buffer: [2][16 t][16 h][4 e] uint2 (f16 i,f,g,o) = 16 KB
    __shared__ uint2 xgl[2][1024];

    if (tid >= 64) {
        // ---------------- producer wave (unchanged from R6) ----------------
        const int e = m & 3, q = m >> 2;
        const int b = b0 + e;
        h16x4 a1[2]; f32x4 c1[2];
#pragma unroll
        for (int nt = 0; nt < 2; ++nt) {
            float4 wv = make_float4(0.f, 0.f, 0.f, 0.f);
            if (hi < 3) wv = *(const float4*)(W1 + (nt * 16 + m) * 12 + 4 * hi);
            a1[nt] = cvt4(wv);
            float4 bv = *(const float4*)(b1 + nt * 16 + 4 * hi);
            c1[nt] = f32x4{bv.x, bv.y, bv.z, bv.w};
        }
        h16x4 a2[4][2];
#pragma unroll
        for (int G = 0; G < 4; ++G) {
            const int gr = G * 16 + m;
#pragma unroll
            for (int s = 0; s < 2; ++s)
                a2[G][s] = cvt4(*(const float4*)(Wih + gr * 32 + s * 16 + 4 * hi));
        }
        const int psA = q * 64 + hi * 16 + e;
        const int psB = (hi ^ q) << 2;
        const float* xrow = x + (size_t)b * 512 * 12 + 4 * hi;

        for (int F = 0; F < 32; ++F) {
            float4 bxp[4];
#pragma unroll
            for (int C = 0; C < 4; ++C)
                if (hi < 3)
                    bxp[C] = *(const float4*)(xrow + (F * 16 + C * 4 + q) * 12);
            uint2* wb = &xgl[F & 1][0];
#pragma unroll
            for (int C = 0; C < 4; ++C) {
                h16x4 bx = {0, 0, 0, 0};
                if (hi < 3) bx = cvt4(bxp[C]);
                f32x4 d0 = __builtin_amdgcn_mfma_f32_16x16x16f16(a1[0], bx, c1[0], 0, 0, 0);
                f32x4 d1 = __builtin_amdgcn_mfma_f32_16x16x16f16(a1[1], bx, c1[1], 0, 0, 0);
                h16x4 u0 = pack4(fmaxf(d0[0], 0.f), fmaxf(d0[1], 0.f),
                                 fmaxf(d0[2], 0.f), fmaxf(d0[3], 0.f));
                h16x4 u1 = pack4(fmaxf(d1[0], 0.f), fmaxf(d1[1], 0.f),
                                 fmaxf(d1[2], 0.f), fmaxf(d1[3], 0.f));
                f32x4 z4 = {0.f, 0.f, 0.f, 0.f};
                f32x4 A0 = __builtin_amdgcn_mfma_f32_16x16x16f16(a2[0][0], u0, z4, 0, 0, 0);
                f32x4 A1 = __builtin_amdgcn_mfma_f32_16x16x16f16(a2[1][0], u0, z4, 0, 0, 0);
                f32x4 A2 = __builtin_amdgcn_mfma_f32_16x16x16f16(a2[2][0], u0, z4, 0, 0, 0);
                f32x4 A3 = __builtin_amdgcn_mfma_f32_16x16x16f16(a2[3][0], u0, z4, 0, 0, 0);
                A0 = __builtin_amdgcn_mfma_f32_16x16x16f16(a2[0][1], u1, A0, 0, 0, 0);
                A1 = __builtin_amdgcn_mfma_f32_16x16x16f16(a2[1][1], u1, A1, 0, 0, 0);
                A2 = __builtin_amdgcn_mfma_f32_16x16x16f16(a2[2][1], u1, A2, 0, 0, 0);
                A3 = __builtin_amdgcn_mfma_f32_16x16x16f16(a2[3][1], u1, A3, 0, 0, 0);
#pragma unroll
                for (int r = 0; r < 4; ++r) {
                    uint2 w_;
                    auto w0 = __builtin_amdgcn_cvt_pkrtz(A0[r], A1[r]);
                    auto w1 = __builtin_amdgcn_cvt_pkrtz(A2[r], A3[r]);
                    w_.x = __builtin_bit_cast(unsigned, w0);
                    w_.y = __builtin_bit_cast(unsigned, w1);
                    wb[psA + C * 256 + (psB ^ (r << 2))] = w_;
                }
            }
            __syncthreads();
        }
    } else {
        // ---------------- consumer wave ----------------
        // NEW mapping: e = m>>2 (element), q = m&3 (replica / owned h-row).
        const int e = m >> 2, q = m & 3;
        const int b = b0 + e;
        const bool q1 = (q & 1) != 0, q2 = (q & 2) != 0;

        h16x4 ar[4]; f32x4 cb[4];
#pragma unroll
        for (int G = 0; G < 4; ++G) {
            const int gr = G * 16 + m;
            ar[G] = cvt4(*(const float4*)(Whh + gr * 16 + 4 * hi));
            float4 bi = *(const float4*)(bih + G * 16 + 4 * hi);
            float4 bh = *(const float4*)(bhh + G * 16 + 4 * hi);
            cb[G] = f32x4{bi.x + bh.x, bi.y + bh.y, bi.z + bh.z, bi.w + bh.w};
        }
        h16x4 hf = cvt4(*(const float4*)(h0 + b * 16 + 4 * hi));
        float cs = c0[b * 16 + 4 * hi + q];
        float hn = 0.f;
        // gate-read slots (same algebra as R5/R6; r == q_c by derivation)
        int va[4];
#pragma unroll
        for (int j = 0; j < 4; ++j) va[j] = hi * 16 + ((q ^ hi ^ j) << 2) + e;

#define STEP(TT, QC) do {                                                      \
    f32x4 di = __builtin_amdgcn_mfma_f32_16x16x16f16(ar[0], hf, cb[0],0,0,0);  \
    f32x4 df = __builtin_amdgcn_mfma_f32_16x16x16f16(ar[1], hf, cb[1],0,0,0);  \
    f32x4 dg = __builtin_amdgcn_mfma_f32_16x16x16f16(ar[2], hf, cb[2],0,0,0);  \
    f32x4 dq = __builtin_amdgcn_mfma_f32_16x16x16f16(ar[3], hf, cb[3],0,0,0);  \
    h16x4 gx = __builtin_bit_cast(h16x4, QC);                                  \
    if ((TT) < 14) QC = bcur[((TT) + 2) * 64 + va[((TT) + 2) & 3]];            \
    float gg = sel4(dg, q1, q2) + (float)gx[2];                                \
    float gi = sel4(di, q1, q2) + (float)gx[0];                                \
    float gf = sel4(df, q1, q2) + (float)gx[1];                                \
    float go = sel4(dq, q1, q2) + (float)gx[3];                                \
    float tg = tanh_fast(gg);                                                  \
    cs = fmaf(sigm(gf), cs, sigm(gi) * tg);                                    \
    hn = sigm(go) * tanh_fast(cs);                                             \
    int hnb = __builtin_bit_cast(int, hn);                                     \
    float j0 = __builtin_bit_cast(float,                                       \
        __builtin_amdgcn_mov_dpp(hnb, 0x00, 0xF, 0xF, true));                  \
    float j1 = __builtin_bit_cast(float,                                       \
        __builtin_amdgcn_mov_dpp(hnb, 0x55, 0xF, 0xF, true));                  \
    float j2 = __builtin_bit_cast(float,                                       \
        __builtin_amdgcn_mov_dpp(hnb, 0xAA, 0xF, 0xF, true));                  \
    float j3 = __builtin_bit_cast(float,                                       \
        __builtin_amdgcn_mov_dpp(hnb, 0xFF, 0xF, 0xF, true));                  \
    hf = pack4(j0, j1, j2, j3);                                                \
} while (0)

        __builtin_amdgcn_s_setprio(1);
        for (int T = 0; T < 32; ++T) {
            __syncthreads();
            const uint2* bcur = &xgl[T & 1][0];
            uint2 qA = bcur[va[0]];
            uint2 qB = bcur[64 + va[1]];
            STEP(0, qA);  STEP(1, qB);
            STEP(2, qA);  STEP(3, qB);
            STEP(4, qA);  STEP(5, qB);
            STEP(6, qA);  STEP(7, qB);
            STEP(8, qA);  STEP(9, qB);
            STEP(10, qA); STEP(11, qB);
            STEP(12, qA); STEP(13, qB);
            STEP(14, qA); STEP(15, qB);
        }
        __builtin_amdgcn_s_setprio(0);
#undef STEP

        // ---- outputs ----
        dout[4096 + b * 16 + 4 * hi + q]         = hn;   // hT [1,B,H]
        dout[4096 + 65536 + b * 16 + 4 * hi + q] = cs;   // cT [1,B,H]
        float p = hn * W2[4 * hi + q];
        p += __shfl_xor(p, 1);
        p += __shfl_xor(p, 2);
        p += __shfl_xor(p, 16);
        p += __shfl_xor(p, 32);
        if (hi == 0 && q == 0) dout[b0 + e] = tanh_fast(p + b2[0]);  // out [B,1]
    }
}

extern "C" void kernel_launch(void* const* d_in, const int* in_sizes, int n_in,
                              void* d_out, int out_size, void* d_ws, size_t ws_size,
                              hipStream_t stream)
{
    const float* x   = (const float*)d_in[0];
    const float* h0  = (const float*)d_in[1];
    const float* c0  = (const float*)d_in[2];
    const float* W1  = (const float*)d_in[3];
    const float* b1  = (const float*)d_in[4];
    const float* Wih = (const float*)d_in[5];
    const float* Whh = (const float*)d_in[6];
    const float* bih = (const float*)d_in[7];
    const float* bhh = (const float*)d_in[8];
    const float* W2  = (const float*)d_in[9];
    const float* b2  = (const float*)d_in[10];
    float* out = (float*)d_out;

    reflex_fused<<<dim3(1024), dim3(128), 0, stream>>>(
        x, h0, c0, W1, b1, Wih, Whh, bih, bhh, W2, b2, out);
}

// Round 8
// 101.877 us; speedup vs baseline: 4.6257x; 1.0028x over previous
//
#include <hip/hip_runtime.h>

typedef __fp16 f16;
typedef __attribute__((ext_vector_type(4))) __fp16 h16x4;
typedef __attribute__((ext_vector_type(4))) float f32x4;

__device__ __forceinline__ float sigm(float x) {
    return __builtin_amdgcn_rcpf(1.0f + __expf(-x));
}
__device__ __forceinline__ float tanh_fast(float x) {
    return 1.0f - 2.0f * __builtin_amdgcn_rcpf(1.0f + __expf(2.0f * x));
}
__device__ __forceinline__ h16x4 cvt4(float4 v) {
    h16x4 r; r[0] = (f16)v.x; r[1] = (f16)v.y; r[2] = (f16)v.z; r[3] = (f16)v.w;
    return r;
}
__device__ __forceinline__ h16x4 pack4(float a, float b, float c, float d) {
    auto p0 = __builtin_amdgcn_cvt_pkrtz(a, b);
    auto p1 = __builtin_amdgcn_cvt_pkrtz(c, d);
    uint2 u = make_uint2(__builtin_bit_cast(unsigned, p0),
                         __builtin_bit_cast(unsigned, p1));
    return __builtin_bit_cast(h16x4, u);
}
__device__ __forceinline__ float sel4(f32x4 v, bool q1, bool q2) {
    float a = q1 ? v[1] : v[0];
    float b = q1 ? v[3] : v[2];
    return q2 ? b : a;
}

// R8: gate tile stored as raw f32x4 C-fragments [t][G][hi][e]; consumer
// feeds them straight into the recurrence MFMA's C operand (bias moved to
// producer's C-init). All consumer LDS reads are ds_read_b128 with
// compile-time immediate offsets (zero address VALU). Producer prefetches
// x one tile ahead. Producer/consumer waves + DPP quad_perm as R7.
__global__ __launch_bounds__(128) void reflex_fused(
    const float* __restrict__ x,
    const float* __restrict__ h0, const float* __restrict__ c0,
    const float* __restrict__ W1, const float* __restrict__ b1,
    const float* __restrict__ Wih, const float* __restrict__ Whh,
    const float* __restrict__ bih, const float* __restrict__ bhh,
    const float* __restrict__ W2, const float* __restrict__ b2,
    float* __restrict__ dout)
{
    const int tid = threadIdx.x;
    const int lane = tid & 63;
    const int m = lane & 15, hi = lane >> 4;
    const int b0 = blockIdx.x << 2;

    // [2 buf][16 t][4 G][4 hi][4 e] f32x4 C-fragments = 32 KB
    __shared__ f32x4 xgl[2][1024];

    if (tid >= 64) {
        // ---------------- producer wave ----------------
        const int e = m & 3, q = m >> 2;
        const int b = b0 + e;
        h16x4 a1[2]; f32x4 c1[2];
#pragma unroll
        for (int nt = 0; nt < 2; ++nt) {
            float4 wv = make_float4(0.f, 0.f, 0.f, 0.f);
            if (hi < 3) wv = *(const float4*)(W1 + (nt * 16 + m) * 12 + 4 * hi);
            a1[nt] = cvt4(wv);
            float4 bv = *(const float4*)(b1 + nt * 16 + 4 * hi);
            c1[nt] = f32x4{bv.x, bv.y, bv.z, bv.w};
        }
        h16x4 a2[4][2]; f32x4 cbp[4];
#pragma unroll
        for (int G = 0; G < 4; ++G) {
            const int gr = G * 16 + m;
#pragma unroll
            for (int s = 0; s < 2; ++s)
                a2[G][s] = cvt4(*(const float4*)(Wih + gr * 32 + s * 16 + 4 * hi));
            float4 bi = *(const float4*)(bih + G * 16 + 4 * hi);
            float4 bh = *(const float4*)(bhh + G * 16 + 4 * hi);
            cbp[G] = f32x4{bi.x + bh.x, bi.y + bh.y, bi.z + bh.z, bi.w + bh.w};
        }
        // per-lane store base (f32x4 units): q*64 + hi*4 + e
        f32x4* pst0 = &xgl[0][q * 64 + hi * 4 + e];
        f32x4* pst1 = &xgl[1][q * 64 + hi * 4 + e];
        // per-lane x pointer: row q of tile 0, k-offset 4*hi
        const float* xp = x + ((size_t)b * 512 + q) * 12 + 4 * hi;
        float4 BXA[4], BXB[4];

#define LOADT(BX) do {                                                         \
    if (hi < 3) {                                                              \
        BX[0] = *(const float4*)(xp);                                          \
        BX[1] = *(const float4*)(xp + 48);                                     \
        BX[2] = *(const float4*)(xp + 96);                                     \
        BX[3] = *(const float4*)(xp + 144);                                    \
    }                                                                          \
    xp += 192;                                                                 \
} while (0)

#define GENSLICE(PST, BXV, CC) do {                                            \
    h16x4 bx = {0, 0, 0, 0};                                                   \
    if (hi < 3) bx = cvt4(BXV);                                                \
    f32x4 d0 = __builtin_amdgcn_mfma_f32_16x16x16f16(a1[0], bx, c1[0],0,0,0);  \
    f32x4 d1 = __builtin_amdgcn_mfma_f32_16x16x16f16(a1[1], bx, c1[1],0,0,0);  \
    h16x4 u0 = pack4(fmaxf(d0[0],0.f), fmaxf(d0[1],0.f),                       \
                     fmaxf(d0[2],0.f), fmaxf(d0[3],0.f));                      \
    h16x4 u1 = pack4(fmaxf(d1[0],0.f), fmaxf(d1[1],0.f),                       \
                     fmaxf(d1[2],0.f), fmaxf(d1[3],0.f));                      \
    f32x4 A0 = __builtin_amdgcn_mfma_f32_16x16x16f16(a2[0][0], u0, cbp[0],0,0,0);\
    f32x4 A1 = __builtin_amdgcn_mfma_f32_16x16x16f16(a2[1][0], u0, cbp[1],0,0,0);\
    f32x4 A2 = __builtin_amdgcn_mfma_f32_16x16x16f16(a2[2][0], u0, cbp[2],0,0,0);\
    f32x4 A3 = __builtin_amdgcn_mfma_f32_16x16x16f16(a2[3][0], u0, cbp[3],0,0,0);\
    A0 = __builtin_amdgcn_mfma_f32_16x16x16f16(a2[0][1], u1, A0, 0, 0, 0);     \
    A1 = __builtin_amdgcn_mfma_f32_16x16x16f16(a2[1][1], u1, A1, 0, 0, 0);     \
    A2 = __builtin_amdgcn_mfma_f32_16x16x16f16(a2[2][1], u1, A2, 0, 0, 0);     \
    A3 = __builtin_amdgcn_mfma_f32_16x16x16f16(a2[3][1], u1, A3, 0, 0, 0);     \
    (PST)[(CC) * 256 +  0] = A0;                                               \
    (PST)[(CC) * 256 + 16] = A1;                                               \
    (PST)[(CC) * 256 + 32] = A2;                                               \
    (PST)[(CC) * 256 + 48] = A3;                                               \
} while (0)

#define GENT(PST, BX) do {                                                     \
    GENSLICE(PST, BX[0], 0); GENSLICE(PST, BX[1], 1);                          \
    GENSLICE(PST, BX[2], 2); GENSLICE(PST, BX[3], 3);                          \
} while (0)

        LOADT(BXA);                       // tile 0
        for (int F2 = 0; F2 < 16; ++F2) {
            LOADT(BXB);                   // tile 2*F2+1
            GENT(pst0, BXA);              // tile 2*F2 -> buf0
            __syncthreads();
            if (F2 < 15) LOADT(BXA);      // tile 2*F2+2
            GENT(pst1, BXB);              // tile 2*F2+1 -> buf1
            __syncthreads();
        }
#undef LOADT
#undef GENSLICE
#undef GENT
    } else {
        // ---------------- consumer wave ----------------
        const int e = m >> 2, q = m & 3;
        const int b = b0 + e;
        const bool q1 = (q & 1) != 0, q2 = (q & 2) != 0;

        h16x4 ar[4];
#pragma unroll
        for (int G = 0; G < 4; ++G)
            ar[G] = cvt4(*(const float4*)(Whh + (G * 16 + m) * 16 + 4 * hi));
        h16x4 hf = cvt4(*(const float4*)(h0 + b * 16 + 4 * hi));
        float cs = c0[b * 16 + 4 * hi + q];
        float hn = 0.f;
        const f32x4* ldsr = &xgl[0][0];
        const int vbi = hi * 4 + e;       // lane part of read index

#define STEP(TT, CF, OFF) do {                                                 \
    f32x4 di = __builtin_amdgcn_mfma_f32_16x16x16f16(ar[0], hf, CF[0],0,0,0);  \
    f32x4 df = __builtin_amdgcn_mfma_f32_16x16x16f16(ar[1], hf, CF[1],0,0,0);  \
    f32x4 dg = __builtin_amdgcn_mfma_f32_16x16x16f16(ar[2], hf, CF[2],0,0,0);  \
    f32x4 dq = __builtin_amdgcn_mfma_f32_16x16x16f16(ar[3], hf, CF[3],0,0,0);  \
    if ((TT) < 14) {                                                           \
        CF[0] = ldsr[(OFF) + ((TT) + 2) * 64 +  0 + vbi];                      \
        CF[1] = ldsr[(OFF) + ((TT) + 2) * 64 + 16 + vbi];                      \
        CF[2] = ldsr[(OFF) + ((TT) + 2) * 64 + 32 + vbi];                      \
        CF[3] = ldsr[(OFF) + ((TT) + 2) * 64 + 48 + vbi];                      \
    }                                                                          \
    float gg = sel4(dg, q1, q2); float gi = sel4(di, q1, q2);                  \
    float gf = sel4(df, q1, q2); float go = sel4(dq, q1, q2);                  \
    float tg = tanh_fast(gg);                                                  \
    cs = fmaf(sigm(gf), cs, sigm(gi) * tg);                                    \
    hn = sigm(go) * tanh_fast(cs);                                             \
    int hnb = __builtin_bit_cast(int, hn);                                     \
    float j0 = __builtin_bit_cast(float,                                       \
        __builtin_amdgcn_mov_dpp(hnb, 0x00, 0xF, 0xF, true));                  \
    float j1 = __builtin_bit_cast(float,                                       \
        __builtin_amdgcn_mov_dpp(hnb, 0x55, 0xF, 0xF, true));                  \
    float j2 = __builtin_bit_cast(float,                                       \
        __builtin_amdgcn_mov_dpp(hnb, 0xAA, 0xF, 0xF, true));                  \
    float j3 = __builtin_bit_cast(float,                                       \
        __builtin_amdgcn_mov_dpp(hnb, 0xFF, 0xF, 0xF, true));                  \
    hf = pack4(j0, j1, j2, j3);                                                \
} while (0)

#define TILEBODY(OFF) do {                                                     \
    f32x4 CA[4], CB[4];                                                        \
    CA[0] = ldsr[(OFF) +  0 + vbi]; CA[1] = ldsr[(OFF) + 16 + vbi];            \
    CA[2] = ldsr[(OFF) + 32 + vbi]; CA[3] = ldsr[(OFF) + 48 + vbi];            \
    CB[0] = ldsr[(OFF) + 64 + vbi]; CB[1] = ldsr[(OFF) + 80 + vbi];            \
    CB[2] = ldsr[(OFF) + 96 + vbi]; CB[3] = ldsr[(OFF) + 112 + vbi];           \
    STEP(0, CA, OFF);  STEP(1, CB, OFF);                                       \
    STEP(2, CA, OFF);  STEP(3, CB, OFF);                                       \
    STEP(4, CA, OFF);  STEP(5, CB, OFF);                                       \
    STEP(6, CA, OFF);  STEP(7, CB, OFF);                                       \
    STEP(8, CA, OFF);  STEP(9, CB, OFF);                                       \
    STEP(10, CA, OFF); STEP(11, CB, OFF);                                      \
    STEP(12, CA, OFF); STEP(13, CB, OFF);                                      \
    STEP(14, CA, OFF); STEP(15, CB, OFF);                                      \
} while (0)

        __builtin_amdgcn_s_setprio(1);
        for (int T2 = 0; T2 < 16; ++T2) {
            __syncthreads();
            TILEBODY(0);
            __syncthreads();
            TILEBODY(1024);
        }
        __builtin_amdgcn_s_setprio(0);
#undef STEP
#undef TILEBODY

        // ---- outputs ----
        dout[4096 + b * 16 + 4 * hi + q]         = hn;   // hT [1,B,H]
        dout[4096 + 65536 + b * 16 + 4 * hi + q] = cs;   // cT [1,B,H]
        float p = hn * W2[4 * hi + q];
        p += __shfl_xor(p, 1);
        p += __shfl_xor(p, 2);
        p += __shfl_xor(p, 16);
        p += __shfl_xor(p, 32);
        if (hi == 0 && q == 0) dout[b0 + e] = tanh_fast(p + b2[0]);  // out [B,1]
    }
}

extern "C" void kernel_launch(void* const* d_in, const int* in_sizes, int n_in,
                              void* d_out, int out_size, void* d_ws, size_t ws_size,
                              hipStream_t stream)
{
    const float* x   = (const float*)d_in[0];
    const float* h0  = (const float*)d_in[1];
    const float* c0  = (const float*)d_in[2];
    const float* W1  = (const float*)d_in[3];
    const float* b1  = (const float*)d_in[4];
    const float* Wih = (const float*)d_in[5];
    const float* Whh = (const float*)d_in[6];
    const float* bih = (const float*)d_in[7];
    const float* bhh = (const float*)d_in[8];
    const float* W2  = (const float*)d_in[9];
    const float* b2  = (const float*)d_in[10];
    float* out = (float*)d_out;

    reflex_fused<<<dim3(1024), dim3(128), 0, stream>>>(
        x, h0, c0, W1, b1, Wih, Whh, bih, bhh, W2, b2, out);
}